// Round 3
// baseline (539.499 us; speedup 1.0000x reference)
//
#include <hip/hip_runtime.h>
#include <hip/hip_bf16.h>

#define N_NODES 50000
#define N_EDGES 800000
#define NC 16
#define FDIM 13
#define HID 32
#define RT_ROW 528   // 16 outputs * 32 hidden + 16 b2-terms
#define EPB 64       // edges per block in k_msg

typedef unsigned short ushort_t;
typedef __attribute__((ext_vector_type(8))) unsigned short u16x8;

__device__ __forceinline__ float bf2f(ushort_t u) {
  union { unsigned int i; float f; } v; v.i = ((unsigned int)u) << 16; return v.f;
}
__device__ __forceinline__ ushort_t f2bf(float f) {
  union { unsigned int i; float f; } v; v.f = f;
  unsigned int r = v.i + 0x7FFFu + ((v.i >> 16) & 1u);   // round-nearest-even
  return (ushort_t)(r >> 16);
}
// dual-dtype input decode: isf32 ? fp32 : bf16 (flag is wave-uniform)
__device__ __forceinline__ float loadf(const void* p, int i, int isf32) {
  return isf32 ? ((const float*)p)[i] : bf2f(((const ushort_t*)p)[i]);
}
__device__ __forceinline__ float sigmoidf_(float x) { return 1.0f / (1.0f + __expf(-x)); }
__device__ __forceinline__ float tanhf_(float x) { return 1.0f - 2.0f / (__expf(2.0f * x) + 1.0f); }

// ---- dtype detector: low 16 bits of each u32 word decoded as bf16.
// bf16-packed N(0,1) data -> sane exponents (~0 wild). fp32 data -> low
// mantissa bits are ~uniform -> ~81% wild. Decide fp32 if wild > 64/256.
__global__ void k_detect(const unsigned int* __restrict__ w, int* __restrict__ flag) {
  __shared__ int cnt;
  if (threadIdx.x == 0) cnt = 0;
  __syncthreads();
  unsigned int lo = w[threadIdx.x] & 0xFFFFu;
  unsigned int ex = (lo >> 7) & 0xFFu;
  int wild = (ex < 103u || ex > 151u) ? 1 : 0;
  if (lo == 0u || lo == 0x8000u) wild = 0;   // exact zero is sane
  atomicAdd(&cnt, wild);
  __syncthreads();
  if (threadIdx.x == 0) flag[0] = (cnt > 64) ? 1 : 0;
}

// ---- hx (input dtype) -> fp32 working copy ----
__global__ void k_init_hx(const void* __restrict__ hx_in, float* __restrict__ hx32,
                          const int* __restrict__ flag) {
  int isf32 = flag[0];
  int i = blockIdx.x * blockDim.x + threadIdx.x;
  if (i < N_NODES * NC) hx32[i] = loadf(hx_in, i, isf32);
}

// ---- degree (into deg buffer, pre-zeroed); then invert in place ----
__global__ void k_deg(const int* __restrict__ dst, float* __restrict__ deg) {
  int e = blockIdx.x * blockDim.x + threadIdx.x;
  if (e < N_EDGES) atomicAdd(&deg[dst[e]], 1.0f);
}
__global__ void k_invdeg(float* deg) {
  int v = blockIdx.x * blockDim.x + threadIdx.x;
  if (v < N_NODES) deg[v] = 1.0f / fmaxf(deg[v], 1.0f);
}

// ---- per-node projection table: Rt[u, o*32+h] = sum_i hx[u,i]*W2[h, i*16+o]
//      Rt[u, 512+o]               = sum_i hx[u,i]*b2[i*16+o]      (Rt is bf16, ours)
__global__ void k_rnode(const float* __restrict__ hx, const void* __restrict__ w2,
                        const void* __restrict__ b2, ushort_t* __restrict__ Rt,
                        const int* __restrict__ flag) {
  __shared__ float w2t[256 * 36];   // [io][h], padded 32->36 to break bank conflicts
  __shared__ float b2s[256];
  int isf32 = flag[0];
  int tid = threadIdx.x;
  for (int k = tid; k < 256 * HID; k += 256) {
    int h = k >> 8, io = k & 255;          // coalesced-ish read of w2 row h
    w2t[io * 36 + h] = loadf(w2, h * 256 + io, isf32);
  }
  b2s[tid] = loadf(b2, tid, isf32);
  __syncthreads();
  int idx = blockIdx.x * 256 + tid;
  if (idx >= N_NODES * NC) return;
  int node = idx >> 4, o = idx & 15;

  float hxr[16];
  const float4* hp = (const float4*)(hx + node * NC);
  #pragma unroll
  for (int q = 0; q < 4; q++) {
    float4 t = hp[q];
    hxr[4 * q + 0] = t.x; hxr[4 * q + 1] = t.y; hxr[4 * q + 2] = t.z; hxr[4 * q + 3] = t.w;
  }

  ushort_t* rowp = Rt + (size_t)node * RT_ROW;
  #pragma unroll
  for (int c = 0; c < 4; c++) {            // h chunk c*8 .. c*8+7
    float a[8] = {0, 0, 0, 0, 0, 0, 0, 0};
    #pragma unroll
    for (int i = 0; i < 16; i++) {
      const float* wp = &w2t[(i * 16 + o) * 36 + c * 8];
      float4 wa = *(const float4*)(wp);
      float4 wb = *(const float4*)(wp + 4);
      a[0] += hxr[i] * wa.x; a[1] += hxr[i] * wa.y; a[2] += hxr[i] * wa.z; a[3] += hxr[i] * wa.w;
      a[4] += hxr[i] * wb.x; a[5] += hxr[i] * wb.y; a[6] += hxr[i] * wb.z; a[7] += hxr[i] * wb.w;
    }
    u16x8 ov;
    #pragma unroll
    for (int j = 0; j < 8; j++) ov[j] = f2bf(a[j]);
    *(u16x8*)(rowp + o * 32 + c * 8) = ov;
  }
  float vb = 0.0f;
  #pragma unroll
  for (int i = 0; i < 16; i++) vb += hxr[i] * b2s[i * 16 + o];
  rowp[512 + o] = f2bf(vb);
}

// ---- fused edge kernel: recompute hidden (fnet layer1) in LDS, then
//      m[e,o] = Rt_b2[src,o] + sum_h hidden[e,h]*Rt[src,o*32+h]; scatter to agg[dst]
__global__ void __launch_bounds__(256) k_msg(
    const int* __restrict__ src, const int* __restrict__ dst,
    const void* __restrict__ ef, const void* __restrict__ w1,
    const void* __restrict__ b1, const ushort_t* __restrict__ Rt,
    float* __restrict__ agg, const int* __restrict__ flag) {
  __shared__ float w1s[FDIM * HID];      // [i][h]
  __shared__ float b1s[HID];
  __shared__ float efs[EPB * FDIM];      // staged edge feats, decoded to fp32
  __shared__ int ssrc[EPB], sdst[EPB];
  __shared__ float hs[EPB * 33];         // hidden, stride 33 to break bank conflicts

  int isf32 = flag[0];
  int tid = threadIdx.x;
  int e0 = blockIdx.x * EPB;

  for (int k = tid; k < FDIM * HID; k += 256) w1s[k] = loadf(w1, k, isf32);
  if (tid < HID) b1s[tid] = loadf(b1, tid, isf32);
  for (int k = tid; k < EPB * FDIM; k += 256) efs[k] = loadf(ef, e0 * FDIM + k, isf32);
  if (tid < EPB) { ssrc[tid] = src[e0 + tid]; sdst[tid] = dst[e0 + tid]; }
  __syncthreads();

  // hidden[le,h] = relu(ef[e0+le,:] @ W1 + b1), fp32
  for (int v = tid; v < EPB * HID; v += 256) {
    int le = v >> 5, h = v & 31;
    float acc = b1s[h];
    #pragma unroll
    for (int i = 0; i < FDIM; i++) acc += efs[le * FDIM + i] * w1s[i * HID + h];
    hs[le * 33 + h] = fmaxf(acc, 0.0f);
  }
  __syncthreads();

  // 64 edges * 16 outputs = 1024 items / 256 threads = 4 each
  #pragma unroll
  for (int q = 0; q < 4; q++) {
    int item = q * 256 + tid;
    int le = item >> 4, o = item & 15;
    int s = ssrc[le], d = sdst[le];
    const ushort_t* rrow = Rt + (size_t)s * RT_ROW;
    const u16x8* rr = (const u16x8*)(rrow + o * 32);
    float acc = bf2f(rrow[512 + o]);
    #pragma unroll
    for (int c = 0; c < 4; c++) {
      u16x8 rv = rr[c];
      #pragma unroll
      for (int j = 0; j < 8; j++) acc += hs[le * 33 + c * 8 + j] * bf2f(rv[j]);
    }
    atomicAdd(&agg[d * NC + o], acc);
  }
}

// ---- GRU cell: one thread per (node, o) ----
__global__ void k_gru(const float* __restrict__ agg, const float* __restrict__ invdeg,
                      const float* __restrict__ hx_old, float* __restrict__ hx_new,
                      const void* __restrict__ w_ih, const void* __restrict__ w_hh,
                      const void* __restrict__ b_ih, const void* __restrict__ b_hh,
                      void* __restrict__ out, int write_out, const int* __restrict__ flag) {
  __shared__ float wih[3 * NC * NC], whh[3 * NC * NC], bih[3 * NC], bhh[3 * NC];
  int isf32 = flag[0];
  int tid = threadIdx.x;
  for (int k = tid; k < 3 * NC * NC; k += 256) {
    wih[k] = loadf(w_ih, k, isf32);
    whh[k] = loadf(w_hh, k, isf32);
  }
  if (tid < 3 * NC) { bih[tid] = loadf(b_ih, tid, isf32); bhh[tid] = loadf(b_hh, tid, isf32); }
  __syncthreads();
  int idx = blockIdx.x * 256 + tid;
  if (idx >= N_NODES * NC) return;
  int v = idx >> 4, o = idx & 15;
  float inv = invdeg[v];
  float x[16], h[16];
  const float4* ar = (const float4*)(agg + v * NC);
  const float4* hr = (const float4*)(hx_old + v * NC);
  #pragma unroll
  for (int q = 0; q < 4; q++) {
    float4 a = ar[q], b = hr[q];
    x[4 * q + 0] = a.x * inv; x[4 * q + 1] = a.y * inv; x[4 * q + 2] = a.z * inv; x[4 * q + 3] = a.w * inv;
    h[4 * q + 0] = b.x; h[4 * q + 1] = b.y; h[4 * q + 2] = b.z; h[4 * q + 3] = b.w;
  }
  float gir = bih[o], giz = bih[NC + o], gin = bih[2 * NC + o];
  float ghr = bhh[o], ghz = bhh[NC + o], ghn = bhh[2 * NC + o];
  #pragma unroll
  for (int k = 0; k < NC; k++) {
    gir += x[k] * wih[o * NC + k];
    giz += x[k] * wih[(NC + o) * NC + k];
    gin += x[k] * wih[(2 * NC + o) * NC + k];
    ghr += h[k] * whh[o * NC + k];
    ghz += h[k] * whh[(NC + o) * NC + k];
    ghn += h[k] * whh[(2 * NC + o) * NC + k];
  }
  float r = sigmoidf_(gir + ghr);
  float z = sigmoidf_(giz + ghz);
  float n = tanhf_(gin + r * ghn);
  float hn = (1.0f - z) * n + z * h[o];
  hx_new[idx] = hn;
  if (write_out) {
    if (isf32) ((float*)out)[idx] = hn;
    else       ((ushort_t*)out)[idx] = f2bf(hn);
  }
}

extern "C" void kernel_launch(void* const* d_in, const int* in_sizes, int n_in,
                              void* d_out, int out_size, void* d_ws, size_t ws_size,
                              hipStream_t stream) {
  const void* hx_in = d_in[0];
  const void* ef    = d_in[1];
  const int*  esrc  = (const int*)d_in[2];
  const int*  edst  = (const int*)d_in[3];
  const void* w1    = d_in[4];
  const void* b1    = d_in[5];
  const void* w2    = d_in[6];
  const void* b2    = d_in[7];
  const void* wih   = d_in[8];
  const void* whh   = d_in[9];
  const void* bih   = d_in[10];
  const void* bhh   = d_in[11];

  // workspace layout (16B-aligned offsets); total = 62.6 MB
  char* ws = (char*)d_ws;
  float*    hxA  = (float*)(ws + 0);           // 3.2 MB
  float*    hxB  = (float*)(ws + 3200000);     // 3.2 MB
  float*    agg  = (float*)(ws + 6400000);     // 3.2 MB
  float*    deg  = (float*)(ws + 9600000);     // 0.2 MB (deg -> inv_deg in place)
  int*      flag = (int*)(ws + 9800000);       // 4 B dtype flag (1 = fp32 inputs)
  ushort_t* Rt   = (ushort_t*)(ws + 9830400);  // N*528*2 = 52.8 MB -> ends 62,630,400

  k_detect<<<1, 256, 0, stream>>>((const unsigned int*)hx_in, flag);
  hipMemsetAsync(deg, 0, N_NODES * sizeof(float), stream);
  k_init_hx<<<(N_NODES * NC + 255) / 256, 256, 0, stream>>>(hx_in, hxA, flag);
  k_deg<<<(N_EDGES + 255) / 256, 256, 0, stream>>>(edst, deg);
  k_invdeg<<<(N_NODES + 255) / 256, 256, 0, stream>>>(deg);

  float* hcur = hxA;
  float* hnext = hxB;
  for (int r = 0; r < 2; r++) {
    k_rnode<<<(N_NODES * NC) / 256, 256, 0, stream>>>(hcur, w2, b2, Rt, flag);
    hipMemsetAsync(agg, 0, N_NODES * NC * sizeof(float), stream);
    k_msg<<<N_EDGES / EPB, 256, 0, stream>>>(esrc, edst, ef, w1, b1, Rt, agg, flag);
    k_gru<<<(N_NODES * NC) / 256, 256, 0, stream>>>(agg, deg, hcur, hnext,
                                                    wih, whh, bih, bhh, d_out, r == 1, flag);
    float* t = hcur; hcur = hnext; hnext = t;
  }
}